// Round 1
// baseline (159.035 us; speedup 1.0000x reference)
//
#include <hip/hip_runtime.h>
#include <math.h>

#define WAY   32
#define QUERY 128
#define FEAT  640
#define NPAIR (WAY * (WAY - 1))   // 992
#define WQ    (WAY * QUERY)       // 4096

static __device__ __forceinline__ float leaky(float v) {
    return v >= 0.0f ? v : 0.2f * v;
}

// K1: A[i,o] = sum_f S[i,f] * W1[o, f]        (half = 0)
//     B[i,o] = sum_f S[i,f] * W1[o, 640 + f]  (half = 1)
// t enumerates (half, o, i) with i fastest: 32 lanes share one W1 row -> broadcast.
__global__ __launch_bounds__(256) void k1_proj(const float* __restrict__ S,
                                               const float* __restrict__ W1,
                                               float* __restrict__ A,
                                               float* __restrict__ B) {
    int t = blockIdx.x * blockDim.x + threadIdx.x;      // [0, 2*640*32)
    int half = t / (WAY * FEAT);
    int rem  = t % (WAY * FEAT);
    int o = rem / WAY;
    int i = rem % WAY;
    const float4* sp = (const float4*)(S + i * FEAT);
    const float4* wp = (const float4*)(W1 + o * (2 * FEAT) + half * FEAT);
    float acc = 0.0f;
#pragma unroll 4
    for (int f4 = 0; f4 < FEAT / 4; ++f4) {
        float4 sv = sp[f4];
        float4 wv = wp[f4];
        acc += sv.x * wv.x + sv.y * wv.y + sv.z * wv.z + sv.w * wv.w;
    }
    float* dst = half ? B : A;
    dst[i * FEAT + o] = acc;
}

// K2: h1[p, f] = leaky(A[i,f] + B[j,f] + b1[f]), p = i*31+jj, j = jj<i ? jj : jj+1
__global__ __launch_bounds__(256) void k2_h1(const float* __restrict__ A,
                                             const float* __restrict__ B,
                                             const float* __restrict__ b1,
                                             float* __restrict__ h1) {
    int t = blockIdx.x * blockDim.x + threadIdx.x;      // [0, 992*640)
    if (t >= NPAIR * FEAT) return;
    int p = t / FEAT;
    int f = t % FEAT;
    int i  = p / (WAY - 1);
    int jj = p % (WAY - 1);
    int j  = (jj < i) ? jj : jj + 1;
    float v = A[i * FEAT + f] + B[j * FEAT + f] + b1[f];
    h1[t] = leaky(v);
}

// K3: h2[p, o] = leaky(sum_f h1[p,f] * W2[o,f] + b2[o])
// Tiled 64x64, TK=16, 256 threads, 4x4 register blocking.
#define TM 64
#define TN 64
#define TK 16
#define LDP 20   // LDS row stride (floats): 80B -> float4-aligned, <=2-way bank aliasing
__global__ __launch_bounds__(256) void k3_gemm(const float* __restrict__ h1,
                                               const float* __restrict__ W2,
                                               const float* __restrict__ b2,
                                               float* __restrict__ h2) {
    __shared__ float shA[TM][LDP];  // h1 tile  [p][k]
    __shared__ float shB[TN][LDP];  // W2 tile  [o][k]
    const int p0 = blockIdx.x * TM;
    const int o0 = blockIdx.y * TN;
    const int tid = threadIdx.x;
    const int tr = tid & 15;   // o-dim (fastest across lanes -> coalesced stores)
    const int tc = tid >> 4;   // p-dim
    const int rr  = tid >> 2;          // 0..63 : row within tile for staging
    const int cc4 = (tid & 3) * 4;     // 0,4,8,12 : k offset (float4)

    float acc[4][4] = {};

    for (int f0 = 0; f0 < FEAT; f0 += TK) {
        // stage h1 tile (guard rows past 992 with zeros)
        int gp = p0 + rr;
        float4 va = make_float4(0.f, 0.f, 0.f, 0.f);
        if (gp < NPAIR) va = *(const float4*)(h1 + gp * FEAT + f0 + cc4);
        *(float4*)&shA[rr][cc4] = va;
        // stage W2 tile (o always in range: 10*64 = 640)
        float4 vb = *(const float4*)(W2 + (o0 + rr) * FEAT + f0 + cc4);
        *(float4*)&shB[rr][cc4] = vb;
        __syncthreads();

#pragma unroll
        for (int k = 0; k < TK; ++k) {
            float a[4], b[4];
#pragma unroll
            for (int r = 0; r < 4; ++r) a[r] = shA[tc + 16 * r][k];
#pragma unroll
            for (int c = 0; c < 4; ++c) b[c] = shB[tr + 16 * c][k];
#pragma unroll
            for (int r = 0; r < 4; ++r)
#pragma unroll
                for (int c = 0; c < 4; ++c)
                    acc[r][c] += a[r] * b[c];
        }
        __syncthreads();
    }

#pragma unroll
    for (int r = 0; r < 4; ++r) {
        int p = p0 + tc + 16 * r;
        if (p >= NPAIR) continue;
#pragma unroll
        for (int c = 0; c < 4; ++c) {
            int o = o0 + tr + 16 * c;
            h2[p * FEAT + o] = leaky(acc[r][c] + b2[o]);
        }
    }
}

// K4: c2[i, o] = (mean_jj h2[i*31+jj, o])^2
__global__ __launch_bounds__(256) void k4_ctx(const float* __restrict__ h2,
                                              float* __restrict__ c2) {
    int t = blockIdx.x * blockDim.x + threadIdx.x;      // [0, 32*640)
    int i = t / FEAT;
    int o = t % FEAT;
    float s = 0.0f;
#pragma unroll 31
    for (int jj = 0; jj < WAY - 1; ++jj)
        s += h2[(i * (WAY - 1) + jj) * FEAT + o];
    float m = s * (1.0f / 31.0f);
    c2[t] = m * m;
}

// K5: out[q*32 + wi] = -sqrt( sum_f ((S[wi,f] - Q[q,f]) * c2[wi,f])^2 )
// wi fastest: Q row broadcast across each 32-lane group; output coalesced.
__global__ __launch_bounds__(256) void k5_dist(const float* __restrict__ S,
                                               const float* __restrict__ c2,
                                               const float* __restrict__ Q,
                                               float* __restrict__ out) {
    int t = blockIdx.x * blockDim.x + threadIdx.x;      // [0, 4096*32)
    int wi = t & (WAY - 1);
    int q  = t >> 5;
    const float4* sp = (const float4*)(S  + wi * FEAT);
    const float4* cp = (const float4*)(c2 + wi * FEAT);
    const float4* qp = (const float4*)(Q  + q * FEAT);
    float acc = 0.0f;
#pragma unroll 4
    for (int f4 = 0; f4 < FEAT / 4; ++f4) {
        float4 sv = sp[f4];
        float4 cv = cp[f4];
        float4 qv = qp[f4];
        float dx = (sv.x - qv.x) * cv.x; acc += dx * dx;
        float dy = (sv.y - qv.y) * cv.y; acc += dy * dy;
        float dz = (sv.z - qv.z) * cv.z; acc += dz * dz;
        float dw = (sv.w - qv.w) * cv.w; acc += dw * dw;
    }
    out[t] = -sqrtf(acc);
}

extern "C" void kernel_launch(void* const* d_in, const int* in_sizes, int n_in,
                              void* d_out, int out_size, void* d_ws, size_t ws_size,
                              hipStream_t stream) {
    const float* S  = (const float*)d_in[0];   // [32, 640]
    const float* Q  = (const float*)d_in[1];   // [32, 128, 640] -> [4096, 640]
    const float* W1 = (const float*)d_in[2];   // [640, 1280]
    const float* b1 = (const float*)d_in[3];   // [640]
    const float* W2 = (const float*)d_in[4];   // [640, 640]
    const float* b2 = (const float*)d_in[5];   // [640]
    float* out = (float*)d_out;                // [4096, 32]

    float* ws = (float*)d_ws;
    float* A   = ws;                               // 32*640
    float* B   = A  + WAY * FEAT;                  // 32*640
    float* h1  = B  + WAY * FEAT;                  // 992*640
    float* h2  = h1 + NPAIR * FEAT;                // 992*640
    float* c2  = h2 + NPAIR * FEAT;                // 32*640
    (void)ws_size; (void)in_sizes; (void)n_in; (void)out_size;

    // K1: 2*640*32 = 40960 threads
    k1_proj<<<dim3(40960 / 256), dim3(256), 0, stream>>>(S, W1, A, B);
    // K2: 992*640 = 634880 threads
    k2_h1<<<dim3((NPAIR * FEAT + 255) / 256), dim3(256), 0, stream>>>(A, B, b1, h1);
    // K3: 16 p-tiles x 10 o-tiles
    k3_gemm<<<dim3((NPAIR + TM - 1) / TM, FEAT / TN), dim3(256), 0, stream>>>(h1, W2, b2, h2);
    // K4: 32*640 = 20480 threads
    k4_ctx<<<dim3(20480 / 256), dim3(256), 0, stream>>>(h2, c2);
    // K5: 4096*32 = 131072 threads
    k5_dist<<<dim3(WQ * WAY / 256), dim3(256), 0, stream>>>(S, c2, Q, out);
}

// Round 2
// 128.066 us; speedup vs baseline: 1.2418x; 1.2418x over previous
//
#include <hip/hip_runtime.h>
#include <math.h>

#define WAY   32
#define QUERY 128
#define FEAT  640
#define NPAIR (WAY * (WAY - 1))   // 992
#define WQ    (WAY * QUERY)       // 4096

static __device__ __forceinline__ float leaky(float v) {
    return v >= 0.0f ? v : 0.2f * v;
}
static __device__ __forceinline__ float dot4(float4 a, float4 b) {
    return a.x * b.x + a.y * b.y + a.z * b.z + a.w * b.w;
}

// ---------------------------------------------------------------------------
// K1: A[i,o] = sum_f S[i,f] * W1[o, f]       B[i,o] = sum_f S[i,f] * W1[o, 640+f]
// 32 lanes share one W1 row (broadcast); S rows are L1/L2-resident.
__global__ __launch_bounds__(256) void k1_proj(const float* __restrict__ S,
                                               const float* __restrict__ W1,
                                               float* __restrict__ A,
                                               float* __restrict__ B) {
    int t = blockIdx.x * blockDim.x + threadIdx.x;      // [0, 2*640*32)
    int half = t / (WAY * FEAT);
    int rem  = t % (WAY * FEAT);
    int o = rem / WAY;
    int i = rem % WAY;
    const float4* sp = (const float4*)(S + i * FEAT);
    const float4* wp = (const float4*)(W1 + o * (2 * FEAT) + half * FEAT);
    float acc = 0.0f;
#pragma unroll 4
    for (int f4 = 0; f4 < FEAT / 4; ++f4) {
        float4 sv = sp[f4];
        float4 wv = wp[f4];
        acc += sv.x * wv.x + sv.y * wv.y + sv.z * wv.z + sv.w * wv.w;
    }
    float* dst = half ? B : A;
    dst[i * FEAT + o] = acc;
}

// ---------------------------------------------------------------------------
// K3 (fused k2+k3): h2[p,o] = leaky( sum_f leaky(A[i,f]+B[j,f]+b1[f]) * W2[o,f] + b2[o] )
// h1 tile computed on the fly during LDS staging (h1 never hits global memory).
// Tile 32(p) x 64(o), TK=32, 256 threads, 2x4 register blocking, ds_read_b128 frags.
#define TM 32
#define TN 64
#define TK 32
#define LDP 36   // LDS row stride (floats); 144 B, float4-aligned
__global__ __launch_bounds__(256) void k3_fused(const float* __restrict__ A,
                                                const float* __restrict__ B,
                                                const float* __restrict__ b1,
                                                const float* __restrict__ W2,
                                                const float* __restrict__ b2,
                                                float* __restrict__ h2) {
    __shared__ float shA[TM][LDP];  // h1 tile [p][k]
    __shared__ float shB[TN][LDP];  // W2 tile [o][k]
    const int p0 = blockIdx.x * TM;   // 31 tiles, 31*32 = 992 exact
    const int o0 = blockIdx.y * TN;   // 10 tiles
    const int tid = threadIdx.x;
    const int tr = tid & 15;          // o-sub
    const int tc = tid >> 4;          // p-sub (0..15)

    float acc[2][4] = {};

    for (int f0 = 0; f0 < FEAT; f0 += TK) {
        __syncthreads();
        // --- stage h1 tile: 32 rows x 32 k = 256 float4, one per thread ---
        {
            int row = tid >> 3;              // 0..31
            int c4  = (tid & 7) << 2;        // 0..28
            int p = p0 + row;
            int i  = p / (WAY - 1);
            int jj = p % (WAY - 1);
            int j  = jj + (jj >= i ? 1 : 0);
            float4 va = *(const float4*)(A + i * FEAT + f0 + c4);
            float4 vb = *(const float4*)(B + j * FEAT + f0 + c4);
            float4 bb = *(const float4*)(b1 + f0 + c4);
            float4 h;
            h.x = leaky(va.x + vb.x + bb.x);
            h.y = leaky(va.y + vb.y + bb.y);
            h.z = leaky(va.z + vb.z + bb.z);
            h.w = leaky(va.w + vb.w + bb.w);
            *(float4*)&shA[row][c4] = h;
        }
        // --- stage W2 tile: 64 rows x 32 k = 512 float4, two per thread ---
#pragma unroll
        for (int s = 0; s < 2; ++s) {
            int slot = tid + 256 * s;
            int row = slot >> 3;             // 0..63
            int c4  = (slot & 7) << 2;
            float4 vb = *(const float4*)(W2 + (o0 + row) * FEAT + f0 + c4);
            *(float4*)&shB[row][c4] = vb;
        }
        __syncthreads();

#pragma unroll
        for (int k4 = 0; k4 < TK / 4; ++k4) {
            int k = k4 << 2;
            float4 a4[2], b4[4];
#pragma unroll
            for (int r = 0; r < 2; ++r) a4[r] = *(const float4*)&shA[tc + 16 * r][k];
#pragma unroll
            for (int c = 0; c < 4; ++c) b4[c] = *(const float4*)&shB[tr + 16 * c][k];
#pragma unroll
            for (int r = 0; r < 2; ++r)
#pragma unroll
                for (int c = 0; c < 4; ++c)
                    acc[r][c] += dot4(a4[r], b4[c]);
        }
    }

#pragma unroll
    for (int r = 0; r < 2; ++r) {
        int p = p0 + tc + 16 * r;
#pragma unroll
        for (int c = 0; c < 4; ++c) {
            int o = o0 + tr + 16 * c;
            h2[p * FEAT + o] = leaky(acc[r][c] + b2[o]);
        }
    }
}

// ---------------------------------------------------------------------------
// K4: per wi: c1 = mean_jj h2, m = c1^4, v = m*S; store transposed [o/4][32][4];
//     alpha[wi] = sum_o m*S^2 (deterministic LDS reduction).
__global__ __launch_bounds__(640) void k4_ctx(const float* __restrict__ h2,
                                              const float* __restrict__ S,
                                              float* __restrict__ v4,
                                              float* __restrict__ m4,
                                              float* __restrict__ alpha) {
    __shared__ float red[10];
    const int wi = blockIdx.x;
    const int o  = threadIdx.x;          // 0..639
    float s = 0.0f;
#pragma unroll 31
    for (int jj = 0; jj < WAY - 1; ++jj)
        s += h2[(wi * (WAY - 1) + jj) * FEAT + o];
    float c1 = s * (1.0f / 31.0f);
    float c2 = c1 * c1;
    float m  = c2 * c2;
    float sv = S[wi * FEAT + o];
    float v  = m * sv;
    int idx4 = ((o >> 2) * WAY + wi) * 4 + (o & 3);
    m4[idx4] = m;
    v4[idx4] = v;

    float part = v * sv;                 // m * S^2
#pragma unroll
    for (int off = 32; off > 0; off >>= 1)
        part += __shfl_down(part, off, 64);
    int lane = o & 63, w = o >> 6;
    if (lane == 0) red[w] = part;
    __syncthreads();
    if (o == 0) {
        float t = 0.0f;
#pragma unroll
        for (int k = 0; k < 10; ++k) t += red[k];
        alpha[wi] = t;
    }
}

// ---------------------------------------------------------------------------
// K5: out[q*32+wi] = -sqrt(max(alpha[wi] - 2*dot(Q_q, v_wi) + dot(Q_q^2, m_wi), 0))
// Block = 16 queries x 32 wi; Q and Q^2 staged in LDS; v4/m4 read coalesced
// ([f4][wi][4] layout -> 32 lanes read 512 B contiguous, L2-resident).
#define FK 160
__global__ __launch_bounds__(256) void k5_dot(const float* __restrict__ Q,
                                              const float* __restrict__ v4,
                                              const float* __restrict__ m4,
                                              const float* __restrict__ alpha,
                                              float* __restrict__ out) {
    __shared__ float shQ[16][FK + 4];
    __shared__ float shQ2[16][FK + 4];
    const int q0 = blockIdx.x * 16;
    const int tid = threadIdx.x;
    const int wi = tid & 31;
    const int ql = tid >> 5;             // 0..7

    float acc1a = 0.f, acc2a = 0.f, acc1b = 0.f, acc2b = 0.f;

    for (int f0 = 0; f0 < FEAT; f0 += FK) {
        __syncthreads();
        for (int idx = tid; idx < 16 * (FK / 2); idx += 256) {
            int row = idx / (FK / 2);
            int m2  = idx % (FK / 2);
            float2 qv = *(const float2*)(Q + (q0 + row) * FEAT + f0 + 2 * m2);
            *(float2*)&shQ[row][2 * m2]  = qv;
            float2 q2 = make_float2(qv.x * qv.x, qv.y * qv.y);
            *(float2*)&shQ2[row][2 * m2] = q2;
        }
        __syncthreads();

#pragma unroll 8
        for (int c = 0; c < FK; c += 4) {
            int fi = f0 + c;
            float4 vv = *(const float4*)(v4 + ((fi >> 2) * WAY + wi) * 4);
            float4 mm = *(const float4*)(m4 + ((fi >> 2) * WAY + wi) * 4);
            float4 qa  = *(const float4*)&shQ[ql][c];
            float4 q2a = *(const float4*)&shQ2[ql][c];
            float4 qb  = *(const float4*)&shQ[ql + 8][c];
            float4 q2b = *(const float4*)&shQ2[ql + 8][c];
            acc1a += dot4(qa, vv);
            acc2a += dot4(q2a, mm);
            acc1b += dot4(qb, vv);
            acc2b += dot4(q2b, mm);
        }
    }

    float aw = alpha[wi];
    float d2a = aw - 2.0f * acc1a + acc2a;
    float d2b = aw - 2.0f * acc1b + acc2b;
    out[(q0 + ql) * WAY + wi]     = -sqrtf(fmaxf(d2a, 0.0f));
    out[(q0 + ql + 8) * WAY + wi] = -sqrtf(fmaxf(d2b, 0.0f));
}

extern "C" void kernel_launch(void* const* d_in, const int* in_sizes, int n_in,
                              void* d_out, int out_size, void* d_ws, size_t ws_size,
                              hipStream_t stream) {
    const float* S  = (const float*)d_in[0];   // [32, 640]
    const float* Q  = (const float*)d_in[1];   // [4096, 640]
    const float* W1 = (const float*)d_in[2];   // [640, 1280]
    const float* b1 = (const float*)d_in[3];   // [640]
    const float* W2 = (const float*)d_in[4];   // [640, 640]
    const float* b2 = (const float*)d_in[5];   // [640]
    float* out = (float*)d_out;                // [4096, 32]

    float* ws = (float*)d_ws;
    float* A     = ws;                         // 32*640
    float* B     = A    + WAY * FEAT;          // 32*640
    float* h2    = B    + WAY * FEAT;          // 992*640
    float* v4    = h2   + NPAIR * FEAT;        // 640*32 (transposed [f/4][wi][4])
    float* m4    = v4   + FEAT * WAY;          // 640*32
    float* alpha = m4   + FEAT * WAY;          // 32
    (void)ws_size; (void)in_sizes; (void)n_in; (void)out_size;

    k1_proj<<<dim3(160), dim3(256), 0, stream>>>(S, W1, A, B);
    k3_fused<<<dim3(NPAIR / TM, FEAT / TN), dim3(256), 0, stream>>>(A, B, b1, W2, b2, h2);
    k4_ctx<<<dim3(WAY), dim3(640), 0, stream>>>(h2, S, v4, m4, alpha);
    k5_dot<<<dim3(WQ / 16), dim3(256), 0, stream>>>(Q, v4, m4, alpha, out);
}

// Round 3
// 76.933 us; speedup vs baseline: 2.0672x; 1.6646x over previous
//
#include <hip/hip_runtime.h>
#include <math.h>

#define WAY   32
#define QUERY 128
#define FEAT  640
#define NPAIR (WAY * (WAY - 1))   // 992
#define WQ    (WAY * QUERY)       // 4096

static __device__ __forceinline__ float leaky(float v) {
    return v >= 0.0f ? v : 0.2f * v;
}
static __device__ __forceinline__ float dot4(float4 a, float4 b) {
    return a.x * b.x + a.y * b.y + a.z * b.z + a.w * b.w;
}

// ---------------------------------------------------------------------------
// K1: A[i,o] = S[i,:] . W1[o, 0:640]     B[i,o] = S[i,:] . W1[o, 640:1280]
// Grid 320 = 2 halves x 160 o-groups(4). Block 256 = 32 i x 4 ol x 2 fh.
// S chunk staged in LDS (pad 33 f4 -> bank-spread); W1 row read per (ol,fh),
// broadcast across the 32 i-lanes. f-split x2 reduced through LDS.
__global__ __launch_bounds__(256) void k1_proj(const float* __restrict__ S,
                                               const float* __restrict__ W1,
                                               float* __restrict__ A,
                                               float* __restrict__ B) {
    __shared__ float4 shS[32][33];
    __shared__ float red1[128];
    const int bx  = blockIdx.x;
    const int half = bx / 160;
    const int o0   = (bx % 160) * 4;
    const int tid = threadIdx.x;
    const int i  = tid & 31;
    const int ol = (tid >> 5) & 3;
    const int fh = tid >> 7;
    const float4* Wrow = (const float4*)(W1 + (o0 + ol) * (2 * FEAT) + half * FEAT);
    float acc = 0.0f;
    for (int f0 = 0; f0 < FEAT; f0 += 128) {
        __syncthreads();
#pragma unroll
        for (int s = 0; s < 4; ++s) {
            int flat = tid + 256 * s;
            int si = flat >> 5, sf = flat & 31;
            shS[si][sf] = *(const float4*)(S + si * FEAT + f0 + 4 * sf);
        }
        __syncthreads();
        const int kb = (f0 >> 2) + fh * 16;
#pragma unroll
        for (int k = 0; k < 16; ++k)
            acc += dot4(shS[i][fh * 16 + k], Wrow[kb + k]);
    }
    if (fh) red1[tid & 127] = acc;
    __syncthreads();
    if (!fh) {
        float tot = acc + red1[tid & 127];
        float* dst = half ? B : A;
        dst[i * FEAT + o0 + ol] = tot;
    }
}

// ---------------------------------------------------------------------------
// K3 (fused k2+k3): h2[p,o] = leaky( sum_f leaky(A[i,f]+B[j,f]+b1[f]) * W2[o,f] + b2[o] )
// Tile 64(p) x 32(o) -> grid 16 x 20 = 320 blocks. acc 4x2 per thread.
// a-frag reads: 4 distinct LDS addrs/wave (16-lane broadcast) -> VALU-bound loop.
#define TM 64
#define TN 32
#define TK 32
#define LDP 36
__global__ __launch_bounds__(256) void k3_fused(const float* __restrict__ A,
                                                const float* __restrict__ B,
                                                const float* __restrict__ b1,
                                                const float* __restrict__ W2,
                                                const float* __restrict__ b2,
                                                float* __restrict__ h2) {
    __shared__ float shA[TM][LDP];
    __shared__ float shB[TN][LDP];
    const int p0 = blockIdx.x * TM;
    const int o0 = blockIdx.y * TN;
    const int tid = threadIdx.x;
    const int tr = tid & 15;     // o-sub
    const int tc = tid >> 4;     // p-sub
    float acc[4][2] = {};

    for (int f0 = 0; f0 < FEAT; f0 += TK) {
        __syncthreads();
        // stage h1 tile on the fly: 64 rows x 32 k = 512 float4, 2/thread
#pragma unroll
        for (int s = 0; s < 2; ++s) {
            int flat = tid + 256 * s;
            int row = flat >> 3;
            int c4  = (flat & 7) << 2;
            int p = p0 + row;
            float4 h = make_float4(0.f, 0.f, 0.f, 0.f);
            if (p < NPAIR) {
                int i  = p / 31;
                int jj = p % 31;
                int j  = jj + (jj >= i ? 1 : 0);
                float4 va = *(const float4*)(A + i * FEAT + f0 + c4);
                float4 vb = *(const float4*)(B + j * FEAT + f0 + c4);
                float4 bb = *(const float4*)(b1 + f0 + c4);
                h.x = leaky(va.x + vb.x + bb.x);
                h.y = leaky(va.y + vb.y + bb.y);
                h.z = leaky(va.z + vb.z + bb.z);
                h.w = leaky(va.w + vb.w + bb.w);
            }
            *(float4*)&shA[row][c4] = h;
        }
        // stage W2 tile: 32 rows x 32 k = 256 float4, 1/thread
        {
            int row = tid >> 3;
            int c4  = (tid & 7) << 2;
            *(float4*)&shB[row][c4] = *(const float4*)(W2 + (o0 + row) * FEAT + f0 + c4);
        }
        __syncthreads();

#pragma unroll
        for (int k4 = 0; k4 < TK / 4; ++k4) {
            int k = k4 << 2;
            float4 a4[4], b4[2];
#pragma unroll
            for (int r = 0; r < 4; ++r) a4[r] = *(const float4*)&shA[tc + 16 * r][k];
#pragma unroll
            for (int c = 0; c < 2; ++c) b4[c] = *(const float4*)&shB[tr + 16 * c][k];
#pragma unroll
            for (int r = 0; r < 4; ++r)
#pragma unroll
                for (int c = 0; c < 2; ++c)
                    acc[r][c] += dot4(a4[r], b4[c]);
        }
    }

#pragma unroll
    for (int r = 0; r < 4; ++r) {
        int p = p0 + tc + 16 * r;
        if (p < NPAIR) {
#pragma unroll
            for (int c = 0; c < 2; ++c) {
                int o = o0 + tr + 16 * c;
                h2[p * FEAT + o] = leaky(acc[r][c] + b2[o]);
            }
        }
    }
}

// ---------------------------------------------------------------------------
// K4: m[wi,o] = (mean_jj h2[wi*31+jj, o])^4 ; emit m and S transposed [f4][wi][4].
// Grid 32 x 10 = 320 blocks; block 256 = 64 o-lanes x 4 jj-groups.
__global__ __launch_bounds__(256) void k4_ctx(const float* __restrict__ h2,
                                              const float* __restrict__ S,
                                              float* __restrict__ s4t,
                                              float* __restrict__ m4t) {
    __shared__ float red[4][64];
    const int wi = blockIdx.x;
    const int o0 = blockIdx.y * 64;
    const int tid = threadIdx.x;
    const int ol = tid & 63;
    const int jg = tid >> 6;
    const int o  = o0 + ol;
    float sum = 0.0f;
#pragma unroll
    for (int t = 0; t < 8; ++t) {
        int jj = jg * 8 + t;
        if (jj < 31) sum += h2[(wi * 31 + jj) * FEAT + o];
    }
    red[jg][ol] = sum;
    __syncthreads();
    if (jg == 0) {
        float c1 = (red[0][ol] + red[1][ol] + red[2][ol] + red[3][ol]) * (1.0f / 31.0f);
        float c2 = c1 * c1;
        float m  = c2 * c2;
        int idx = ((o >> 2) * WAY + wi) * 4 + (o & 3);
        m4t[idx] = m;
        s4t[idx] = S[wi * FEAT + o];
    }
}

// ---------------------------------------------------------------------------
// K5: out[q*32+wi] = -sqrt( sum_f m[wi,f] * (Q[q,f] - S[wi,f])^2 )
// Grid 512 (8 q each); block 256 = 32 wi x 8 qg. All inner-loop operands in
// LDS: q reads broadcast across 32 wi-lanes; s/m reads lane-contiguous.
__global__ __launch_bounds__(256) void k5_dist(const float* __restrict__ Q,
                                               const float* __restrict__ s4t,
                                               const float* __restrict__ m4t,
                                               float* __restrict__ out) {
    __shared__ float4 shQ[8 * 20];
    __shared__ float4 shS[20 * 32];
    __shared__ float4 shM[20 * 32];
    const int q0 = blockIdx.x * 8;
    const int tid = threadIdx.x;
    const int wi = tid & 31;
    const int qg = tid >> 5;
    const float4* Q4 = (const float4*)Q;
    const float4* S4 = (const float4*)s4t;
    const float4* M4 = (const float4*)m4t;
    float accA = 0.f, accB = 0.f;

    for (int c = 0; c < 8; ++c) {
        int f0q = c * 20;     // float4 offset within a 640-float row
        __syncthreads();
        if (tid < 160) {
            int row = tid / 20, kk = tid % 20;
            shQ[tid] = Q4[(q0 + row) * (FEAT / 4) + f0q + kk];
        }
#pragma unroll
        for (int s = 0; s < 3; ++s) {
            int flat = tid + 256 * s;
            if (flat < 640) {
                shS[flat] = S4[f0q * 32 + flat];
                shM[flat] = M4[f0q * 32 + flat];
            }
        }
        __syncthreads();
#pragma unroll
        for (int kk = 0; kk < 20; ++kk) {
            float4 qv = shQ[qg * 20 + kk];
            float4 sv = shS[kk * 32 + wi];
            float4 mv = shM[kk * 32 + wi];
            float dx = qv.x - sv.x;
            float dy = qv.y - sv.y;
            float dz = qv.z - sv.z;
            float dw = qv.w - sv.w;
            accA += (mv.x * dx) * dx;
            accB += (mv.y * dy) * dy;
            accA += (mv.z * dz) * dz;
            accB += (mv.w * dw) * dw;
        }
    }
    out[(q0 + qg) * WAY + wi] = -sqrtf(fmaxf(accA + accB, 0.0f));
}

extern "C" void kernel_launch(void* const* d_in, const int* in_sizes, int n_in,
                              void* d_out, int out_size, void* d_ws, size_t ws_size,
                              hipStream_t stream) {
    const float* S  = (const float*)d_in[0];   // [32, 640]
    const float* Q  = (const float*)d_in[1];   // [4096, 640]
    const float* W1 = (const float*)d_in[2];   // [640, 1280]
    const float* b1 = (const float*)d_in[3];   // [640]
    const float* W2 = (const float*)d_in[4];   // [640, 640]
    const float* b2 = (const float*)d_in[5];   // [640]
    float* out = (float*)d_out;                // [4096, 32]

    float* ws = (float*)d_ws;
    float* A    = ws;                          // 32*640
    float* B    = A   + WAY * FEAT;            // 32*640
    float* h2   = B   + WAY * FEAT;            // 992*640
    float* s4t  = h2  + NPAIR * FEAT;          // 640*32 transposed
    float* m4t  = s4t + FEAT * WAY;            // 640*32 transposed
    (void)ws_size; (void)in_sizes; (void)n_in; (void)out_size;

    k1_proj<<<dim3(320), dim3(256), 0, stream>>>(S, W1, A, B);
    k3_fused<<<dim3(16, 20), dim3(256), 0, stream>>>(A, B, b1, W2, b2, h2);
    k4_ctx<<<dim3(WAY, 10), dim3(256), 0, stream>>>(h2, S, s4t, m4t);
    k5_dist<<<dim3(WQ / 8), dim3(256), 0, stream>>>(Q, s4t, m4t, out);
}

// Round 4
// 62.659 us; speedup vs baseline: 2.5381x; 1.2278x over previous
//
#include <hip/hip_runtime.h>
#include <math.h>

#define WAY   32
#define QUERY 128
#define FEAT  640
#define NPAIR 992
#define WQ    4096

typedef short bf16x8 __attribute__((ext_vector_type(8)));
typedef float f32x4  __attribute__((ext_vector_type(4)));

static __device__ __forceinline__ float leaky(float v) {
    return v >= 0.0f ? v : 0.2f * v;
}
static __device__ __forceinline__ float dot4(float4 a, float4 b) {
    return a.x * b.x + a.y * b.y + a.z * b.z + a.w * b.w;
}
// round-to-nearest-even bf16 bit pattern
static __device__ __forceinline__ unsigned bf16_rne(float x) {
    unsigned u = __builtin_bit_cast(unsigned, x);
    return (u + 0x7FFFu + ((u >> 16) & 1u)) >> 16;
}
// split x ~= hi + lo (both bf16); |x - hi - lo| <= 2^-18 |x|
static __device__ __forceinline__ void split2(float x, short& hi, short& lo) {
    unsigned h = bf16_rne(x);
    float fh = __builtin_bit_cast(float, h << 16);
    hi = (short)h;
    lo = (short)bf16_rne(x - fh);
}

// ---------------------------------------------------------------------------
// K1: A[i,o] = S[i,:] . W1[o,0:640]   B[i,o] = S[i,:] . W1[o,640:1280]
__global__ __launch_bounds__(256) void k1_proj(const float* __restrict__ S,
                                               const float* __restrict__ W1,
                                               float* __restrict__ A,
                                               float* __restrict__ B) {
    __shared__ float4 shS[32][33];
    __shared__ float red1[128];
    const int bx  = blockIdx.x;
    const int half = bx / 160;
    const int o0   = (bx % 160) * 4;
    const int tid = threadIdx.x;
    const int i  = tid & 31;
    const int ol = (tid >> 5) & 3;
    const int fh = tid >> 7;
    const float4* Wrow = (const float4*)(W1 + (o0 + ol) * (2 * FEAT) + half * FEAT);
    float acc = 0.0f;
    for (int f0 = 0; f0 < FEAT; f0 += 128) {
        __syncthreads();
#pragma unroll
        for (int s = 0; s < 4; ++s) {
            int flat = tid + 256 * s;
            int si = flat >> 5, sf = flat & 31;
            shS[si][sf] = *(const float4*)(S + si * FEAT + f0 + 4 * sf);
        }
        __syncthreads();
        const int kb = (f0 >> 2) + fh * 16;
#pragma unroll
        for (int k = 0; k < 16; ++k)
            acc += dot4(shS[i][fh * 16 + k], Wrow[kb + k]);
    }
    if (fh) red1[tid & 127] = acc;
    __syncthreads();
    if (!fh) {
        float tot = acc + red1[tid & 127];
        float* dst = half ? B : A;
        dst[i * FEAT + o0 + ol] = tot;
    }
}

// ---------------------------------------------------------------------------
// K2W: pre-split W2 into hi/lo bf16 (once; removes per-p-tile split VALU in k3)
__global__ __launch_bounds__(256) void k2w_split(const float* __restrict__ W2,
                                                 unsigned short* __restrict__ whi,
                                                 unsigned short* __restrict__ wlo) {
    int t = blockIdx.x * 256 + threadIdx.x;     // [0, 640*640)
    float x = W2[t];
    unsigned h = bf16_rne(x);
    float fh = __builtin_bit_cast(float, h << 16);
    whi[t] = (unsigned short)h;
    wlo[t] = (unsigned short)bf16_rne(x - fh);
}

// ---------------------------------------------------------------------------
// K3: h2[p,o] = leaky( h1[p,:] @ W2[o,:] + b2[o] ),  h1 = leaky(A[i]+B[j]+b1)
// bf16x3 MFMA (hi*hi + hi*lo + lo*hi), 16x16x32. Block 128 thr = 2 waves,
// block-tile 32(p) x 64(o), grid 31 x 10. LDS frag layout [kc][row][16B] ->
// every frag read is a linear 1KB wave read (conflict-free). Reg-prefetch
// pipeline: global loads for step t+1 issue between the barriers of step t.
__global__ __launch_bounds__(128) void k3_mfma(const float* __restrict__ Ap,
                                               const float* __restrict__ Bp,
                                               const float* __restrict__ b1,
                                               const unsigned short* __restrict__ whi,
                                               const unsigned short* __restrict__ wlo,
                                               const float* __restrict__ b2,
                                               float* __restrict__ h2) {
    __shared__ __align__(16) short lsA[2][4][32][8];   // [hi/lo][kc][p-row][8 bf16]
    __shared__ __align__(16) short lsB[2][4][64][8];   // [hi/lo][kc][o-row][8 bf16]
    const int p0 = blockIdx.x * 32;
    const int o0 = blockIdx.y * 64;
    const int tid  = threadIdx.x;
    const int wave = tid >> 6;          // 0..1 -> o-half
    const int lane = tid & 63;
    const int l15 = lane & 15, l4 = lane >> 4;

    // staging coords
    const int arow = tid & 31;          // p-local row
    const int akc  = (tid >> 5) & 3;    // k-chunk 0..3
    const int brow = tid & 63;          // o-local row
    const int bkc  = tid >> 6;          // 0..1 (second chunk at +2)

    const int p = p0 + arow;
    const int ia = p / 31;
    const int jj = p % 31;
    const int ja = jj + (jj >= ia ? 1 : 0);
    const float4*  Ar  = (const float4*)(Ap + ia * FEAT);
    const float4*  Br  = (const float4*)(Bp + ja * FEAT);
    const float4*  b1r = (const float4*)b1;
    const bf16x8*  Whr = (const bf16x8*)(whi + (size_t)(o0 + brow) * FEAT);
    const bf16x8*  Wlr = (const bf16x8*)(wlo + (size_t)(o0 + brow) * FEAT);

    float4 va0, va1, vb0, vb1, bb0, bb1;
    bf16x8 wh0, wh1, wl0, wl1;

    // prefetch t = 0
    {
        int ac = akc * 2;
        va0 = Ar[ac];  va1 = Ar[ac + 1];
        vb0 = Br[ac];  vb1 = Br[ac + 1];
        bb0 = b1r[ac]; bb1 = b1r[ac + 1];
        int wc = bkc;
        wh0 = Whr[wc]; wh1 = Whr[wc + 2];
        wl0 = Wlr[wc]; wl1 = Wlr[wc + 2];
    }

    f32x4 acc[2][2] = {};   // [rt][ct] 16x16 C-tiles; wave-tile 32(p) x 32(o)

    for (int t = 0; t < FEAT / 32; ++t) {
        // ---- write phase: h1 compute + split + LDS store (uses regs of step t)
        float hv[8];
        hv[0] = leaky(va0.x + vb0.x + bb0.x);
        hv[1] = leaky(va0.y + vb0.y + bb0.y);
        hv[2] = leaky(va0.z + vb0.z + bb0.z);
        hv[3] = leaky(va0.w + vb0.w + bb0.w);
        hv[4] = leaky(va1.x + vb1.x + bb1.x);
        hv[5] = leaky(va1.y + vb1.y + bb1.y);
        hv[6] = leaky(va1.z + vb1.z + bb1.z);
        hv[7] = leaky(va1.w + vb1.w + bb1.w);
        bf16x8 ahi, alo;
#pragma unroll
        for (int j = 0; j < 8; ++j) {
            short h, l;
            split2(hv[j], h, l);
            ahi[j] = h; alo[j] = l;
        }
        *(bf16x8*)&lsA[0][akc][arow][0] = ahi;
        *(bf16x8*)&lsA[1][akc][arow][0] = alo;
        *(bf16x8*)&lsB[0][bkc][brow][0]     = wh0;
        *(bf16x8*)&lsB[1][bkc][brow][0]     = wl0;
        *(bf16x8*)&lsB[0][bkc + 2][brow][0] = wh1;
        *(bf16x8*)&lsB[1][bkc + 2][brow][0] = wl1;
        __syncthreads();

        // ---- prefetch step t+1 (overlaps mfma below)
        if (t < FEAT / 32 - 1) {
            int ac = (t + 1) * 8 + akc * 2;
            va0 = Ar[ac];  va1 = Ar[ac + 1];
            vb0 = Br[ac];  vb1 = Br[ac + 1];
            bb0 = b1r[ac]; bb1 = b1r[ac + 1];
            int wc = (t + 1) * 4 + bkc;
            wh0 = Whr[wc]; wh1 = Whr[wc + 2];
            wl0 = Wlr[wc]; wl1 = Wlr[wc + 2];
        }

        // ---- compute phase: frag reads (linear 1KB, conflict-free) + 12 mfma
        bf16x8 aHi[2], aLo[2], bHi[2], bLo[2];
#pragma unroll
        for (int rt = 0; rt < 2; ++rt) {
            aHi[rt] = *(const bf16x8*)&lsA[0][l4][rt * 16 + l15][0];
            aLo[rt] = *(const bf16x8*)&lsA[1][l4][rt * 16 + l15][0];
        }
#pragma unroll
        for (int ct = 0; ct < 2; ++ct) {
            bHi[ct] = *(const bf16x8*)&lsB[0][l4][wave * 32 + ct * 16 + l15][0];
            bLo[ct] = *(const bf16x8*)&lsB[1][l4][wave * 32 + ct * 16 + l15][0];
        }
#pragma unroll
        for (int rt = 0; rt < 2; ++rt)
#pragma unroll
            for (int ct = 0; ct < 2; ++ct) {
                acc[rt][ct] = __builtin_amdgcn_mfma_f32_16x16x32_bf16(aHi[rt], bHi[ct], acc[rt][ct], 0, 0, 0);
                acc[rt][ct] = __builtin_amdgcn_mfma_f32_16x16x32_bf16(aHi[rt], bLo[ct], acc[rt][ct], 0, 0, 0);
                acc[rt][ct] = __builtin_amdgcn_mfma_f32_16x16x32_bf16(aLo[rt], bHi[ct], acc[rt][ct], 0, 0, 0);
            }
        __syncthreads();
    }

    // ---- epilogue: C/D layout col=lane&15, row=(lane>>4)*4+reg
#pragma unroll
    for (int ct = 0; ct < 2; ++ct) {
        const int oo = o0 + wave * 32 + ct * 16 + l15;
        const float b2v = b2[oo];
#pragma unroll
        for (int rt = 0; rt < 2; ++rt) {
#pragma unroll
            for (int r = 0; r < 4; ++r) {
                const int pp = p0 + rt * 16 + l4 * 4 + r;
                h2[pp * FEAT + oo] = leaky(acc[rt][ct][r] + b2v);
            }
        }
    }
}

// ---------------------------------------------------------------------------
// K4: m[wi,o] = (mean_jj h2[wi*31+jj, o])^4 ; emit m and S transposed [f4][wi][4].
__global__ __launch_bounds__(256) void k4_ctx(const float* __restrict__ h2,
                                              const float* __restrict__ S,
                                              float* __restrict__ s4t,
                                              float* __restrict__ m4t) {
    __shared__ float red[4][64];
    const int wi = blockIdx.x;
    const int o0 = blockIdx.y * 64;
    const int tid = threadIdx.x;
    const int ol = tid & 63;
    const int jg = tid >> 6;
    const int o  = o0 + ol;
    float sum = 0.0f;
#pragma unroll
    for (int t = 0; t < 8; ++t) {
        int jj = jg * 8 + t;
        if (jj < 31) sum += h2[(wi * 31 + jj) * FEAT + o];
    }
    red[jg][ol] = sum;
    __syncthreads();
    if (jg == 0) {
        float c1 = (red[0][ol] + red[1][ol] + red[2][ol] + red[3][ol]) * (1.0f / 31.0f);
        float c2 = c1 * c1;
        float m  = c2 * c2;
        int idx = ((o >> 2) * WAY + wi) * 4 + (o & 3);
        m4t[idx] = m;
        s4t[idx] = S[wi * FEAT + o];
    }
}

// ---------------------------------------------------------------------------
// K5: out[q*32+wi] = -sqrt( sum_f m[wi,f] * (Q[q,f] - S[wi,f])^2 )
__global__ __launch_bounds__(256) void k5_dist(const float* __restrict__ Q,
                                               const float* __restrict__ s4t,
                                               const float* __restrict__ m4t,
                                               float* __restrict__ out) {
    __shared__ float4 shQ[8 * 20];
    __shared__ float4 shS[20 * 32];
    __shared__ float4 shM[20 * 32];
    const int q0 = blockIdx.x * 8;
    const int tid = threadIdx.x;
    const int wi = tid & 31;
    const int qg = tid >> 5;
    const float4* Q4 = (const float4*)Q;
    const float4* S4 = (const float4*)s4t;
    const float4* M4 = (const float4*)m4t;
    float accA = 0.f, accB = 0.f;

    for (int c = 0; c < 8; ++c) {
        int f0q = c * 20;
        __syncthreads();
        if (tid < 160) {
            int row = tid / 20, kk = tid % 20;
            shQ[tid] = Q4[(q0 + row) * (FEAT / 4) + f0q + kk];
        }
#pragma unroll
        for (int s = 0; s < 3; ++s) {
            int flat = tid + 256 * s;
            if (flat < 640) {
                shS[flat] = S4[f0q * 32 + flat];
                shM[flat] = M4[f0q * 32 + flat];
            }
        }
        __syncthreads();
#pragma unroll
        for (int kk = 0; kk < 20; ++kk) {
            float4 qv = shQ[qg * 20 + kk];
            float4 sv = shS[kk * 32 + wi];
            float4 mv = shM[kk * 32 + wi];
            float dx = qv.x - sv.x;
            float dy = qv.y - sv.y;
            float dz = qv.z - sv.z;
            float dw = qv.w - sv.w;
            accA += (mv.x * dx) * dx;
            accB += (mv.y * dy) * dy;
            accA += (mv.z * dz) * dz;
            accB += (mv.w * dw) * dw;
        }
    }
    out[(q0 + qg) * WAY + wi] = -sqrtf(fmaxf(accA + accB, 0.0f));
}

extern "C" void kernel_launch(void* const* d_in, const int* in_sizes, int n_in,
                              void* d_out, int out_size, void* d_ws, size_t ws_size,
                              hipStream_t stream) {
    const float* S  = (const float*)d_in[0];   // [32, 640]
    const float* Q  = (const float*)d_in[1];   // [4096, 640]
    const float* W1 = (const float*)d_in[2];   // [640, 1280]
    const float* b1 = (const float*)d_in[3];   // [640]
    const float* W2 = (const float*)d_in[4];   // [640, 640]
    const float* b2 = (const float*)d_in[5];   // [640]
    float* out = (float*)d_out;                // [4096, 32]

    char* wsb = (char*)d_ws;
    float* A    = (float*)wsb;                                    // 32*640
    float* B    = A + WAY * FEAT;                                 // 32*640
    float* h2   = B + WAY * FEAT;                                 // 992*640
    float* s4t  = h2 + NPAIR * FEAT;                              // 640*32
    float* m4t  = s4t + FEAT * WAY;                               // 640*32
    unsigned short* whi = (unsigned short*)(m4t + FEAT * WAY);    // 640*640 u16
    unsigned short* wlo = whi + FEAT * FEAT;                      // 640*640 u16
    (void)ws_size; (void)in_sizes; (void)n_in; (void)out_size;

    k2w_split<<<dim3(FEAT * FEAT / 256), dim3(256), 0, stream>>>(W2, whi, wlo);
    k1_proj<<<dim3(320), dim3(256), 0, stream>>>(S, W1, A, B);
    k3_mfma<<<dim3(NPAIR / 32, FEAT / 64), dim3(128), 0, stream>>>(A, B, b1, whi, wlo, b2, h2);
    k4_ctx<<<dim3(WAY, 10), dim3(256), 0, stream>>>(h2, S, s4t, m4t);
    k5_dist<<<dim3(WQ / 8), dim3(256), 0, stream>>>(Q, s4t, m4t, out);
}

// Round 5
// 45.727 us; speedup vs baseline: 3.4779x; 1.3703x over previous
//
#include <hip/hip_runtime.h>
#include <math.h>

#define WAY   32
#define QUERY 128
#define FEAT  640
#define NPAIR 992
#define WQ    4096

typedef short bf16x8  __attribute__((ext_vector_type(8)));
typedef short short4v __attribute__((ext_vector_type(4)));
typedef float f32x4   __attribute__((ext_vector_type(4)));

static __device__ __forceinline__ float leaky(float v) {
    return v >= 0.0f ? v : 0.2f * v;
}
static __device__ __forceinline__ float dot4(float4 a, float4 b) {
    return a.x * b.x + a.y * b.y + a.z * b.z + a.w * b.w;
}
static __device__ __forceinline__ unsigned bf16_rne(float x) {
    unsigned u = __builtin_bit_cast(unsigned, x);
    return (u + 0x7FFFu + ((u >> 16) & 1u)) >> 16;
}
static __device__ __forceinline__ void split2(float x, short& hi, short& lo) {
    unsigned h = bf16_rne(x);
    float fh = __builtin_bit_cast(float, h << 16);
    hi = (short)h;
    lo = (short)bf16_rne(x - fh);
}

// ---------------------------------------------------------------------------
// K_PRE (fused): blocks 0..319: A'[i,o] = S[i].W1[o,0:640] + b1[o],
//                               B'[i,o] = S[i].W1[o,640:1280]
//                blocks 320..719: split W2 -> whi/wlo bf16 (4 elems/thread)
__global__ __launch_bounds__(256) void k_pre(const float* __restrict__ S,
                                             const float* __restrict__ W1,
                                             const float* __restrict__ b1,
                                             const float* __restrict__ W2,
                                             float* __restrict__ A,
                                             float* __restrict__ B,
                                             unsigned short* __restrict__ whi,
                                             unsigned short* __restrict__ wlo) {
    const int bx = blockIdx.x;
    const int tid = threadIdx.x;
    if (bx < 320) {
        __shared__ float4 shS[32][33];
        __shared__ float red1[128];
        const int half = bx / 160;
        const int o0   = (bx % 160) * 4;
        const int i  = tid & 31;
        const int ol = (tid >> 5) & 3;
        const int fh = tid >> 7;
        const float4* Wrow = (const float4*)(W1 + (o0 + ol) * (2 * FEAT) + half * FEAT);
        float acc = 0.0f;
        for (int f0 = 0; f0 < FEAT; f0 += 128) {
            __syncthreads();
#pragma unroll
            for (int s = 0; s < 4; ++s) {
                int flat = tid + 256 * s;
                int si = flat >> 5, sf = flat & 31;
                shS[si][sf] = *(const float4*)(S + si * FEAT + f0 + 4 * sf);
            }
            __syncthreads();
            const int kb = (f0 >> 2) + fh * 16;
#pragma unroll
            for (int k = 0; k < 16; ++k)
                acc += dot4(shS[i][fh * 16 + k], Wrow[kb + k]);
        }
        if (fh) red1[tid & 127] = acc;
        __syncthreads();
        if (!fh) {
            float tot = acc + red1[tid & 127];
            if (half == 0) A[i * FEAT + o0 + ol] = tot + b1[o0 + ol];
            else           B[i * FEAT + o0 + ol] = tot;
        }
    } else {
        int e = (bx - 320) * 1024 + tid * 4;
        float4 w = *(const float4*)(W2 + e);
        short h0, l0, h1, l1, h2, l2, h3, l3;
        split2(w.x, h0, l0); split2(w.y, h1, l1);
        split2(w.z, h2, l2); split2(w.w, h3, l3);
        short4v hv = {h0, h1, h2, h3};
        short4v lv = {l0, l1, l2, l3};
        *(short4v*)(whi + e) = hv;
        *(short4v*)(wlo + e) = lv;
    }
}

// ---------------------------------------------------------------------------
// K3 v2: h2[p,o] = leaky( h1[p,:] @ W2[o,:] + b2[o] ),  h1 = leaky(A'[i]+B'[j])
// bf16x3 MFMA 16x16x32. Block 256 thr = 4 waves (wave -> o-quarter of 16).
// Tile 32p x 64o, TK=32, grid 31x10. Double-buffered LDS, ONE barrier/step:
//   write(t) -> barrier -> prefetch(t+1) -> compute(t). write(t+1) goes to the
//   other buffer, so stragglers computing (t) are safe; write(t+2) is fenced
//   by barrier(t+1).
__global__ __launch_bounds__(256) void k3_mfma(const float* __restrict__ Ap,
                                               const float* __restrict__ Bp,
                                               const unsigned short* __restrict__ whi,
                                               const unsigned short* __restrict__ wlo,
                                               const float* __restrict__ b2,
                                               float* __restrict__ h2) {
    __shared__ __align__(16) short lsA[2][2][4][32][8];  // [buf][hi/lo][kc][prow][8]
    __shared__ __align__(16) short lsB[2][2][4][64][8];  // [buf][hi/lo][kc][orow][8]
    const int p0 = blockIdx.x * 32;
    const int o0 = blockIdx.y * 64;
    const int tid = threadIdx.x;
    const int w    = tid >> 6;
    const int lane = tid & 63;
    const int l15 = lane & 15, l4 = lane >> 4;

    // A-staging coords: 32 rows x 32 k, one float4 (4 k) per thread
    const int ar  = tid >> 3;            // 0..31
    const int ac4 = (tid & 7) << 2;      // 0,4,..,28
    const int akc = ac4 >> 3;            // k-chunk 0..3
    const int aof = ac4 & 7;             // 0 or 4
    const int p = p0 + ar;
    const int ia = p / 31;
    const int jj = p % 31;
    const int ja = jj + (jj >= ia ? 1 : 0);
    const float* Arow = Ap + ia * FEAT;  // b1 already folded in
    const float* Brow = Bp + ja * FEAT;
    // B-staging coords: 64 rows x 32 k, one bf16x8 per thread per array
    const int br = tid >> 2;             // 0..63
    const int bk = tid & 3;              // kc 0..3
    const unsigned short* Whr = whi + (size_t)(o0 + br) * FEAT;
    const unsigned short* Wlr = wlo + (size_t)(o0 + br) * FEAT;

    float4 ra, rb;
    bf16x8 rwh, rwl;
    ra  = *(const float4*)(Arow + ac4);
    rb  = *(const float4*)(Brow + ac4);
    rwh = *(const bf16x8*)(Whr + bk * 8);
    rwl = *(const bf16x8*)(Wlr + bk * 8);

    f32x4 acc[2] = {};   // rt (two 16-row p-halves) x wave's 16-o quarter

    for (int t = 0; t < FEAT / 32; ++t) {
        const int buf = t & 1;
        // ---- write phase: h1 compute + split + LDS store
        {
            float h[4];
            h[0] = leaky(ra.x + rb.x);
            h[1] = leaky(ra.y + rb.y);
            h[2] = leaky(ra.z + rb.z);
            h[3] = leaky(ra.w + rb.w);
            short hi[4], lo[4];
#pragma unroll
            for (int j = 0; j < 4; ++j) split2(h[j], hi[j], lo[j]);
            *(short4v*)&lsA[buf][0][akc][ar][aof] = (short4v){hi[0], hi[1], hi[2], hi[3]};
            *(short4v*)&lsA[buf][1][akc][ar][aof] = (short4v){lo[0], lo[1], lo[2], lo[3]};
            *(bf16x8*)&lsB[buf][0][bk][br][0] = rwh;
            *(bf16x8*)&lsB[buf][1][bk][br][0] = rwl;
        }
        __syncthreads();
        // ---- prefetch t+1 (overlaps compute below)
        if (t < FEAT / 32 - 1) {
            const int f0 = (t + 1) * 32;
            ra  = *(const float4*)(Arow + f0 + ac4);
            rb  = *(const float4*)(Brow + f0 + ac4);
            rwh = *(const bf16x8*)(Whr + f0 + bk * 8);
            rwl = *(const bf16x8*)(Wlr + f0 + bk * 8);
        }
        // ---- compute: frag reads (linear, conflict-free) + 6 mfma
        bf16x8 ah[2], al[2], bh, bl;
#pragma unroll
        for (int rt = 0; rt < 2; ++rt) {
            ah[rt] = *(const bf16x8*)&lsA[buf][0][l4][rt * 16 + l15][0];
            al[rt] = *(const bf16x8*)&lsA[buf][1][l4][rt * 16 + l15][0];
        }
        bh = *(const bf16x8*)&lsB[buf][0][l4][w * 16 + l15][0];
        bl = *(const bf16x8*)&lsB[buf][1][l4][w * 16 + l15][0];
#pragma unroll
        for (int rt = 0; rt < 2; ++rt) {
            acc[rt] = __builtin_amdgcn_mfma_f32_16x16x32_bf16(ah[rt], bh, acc[rt], 0, 0, 0);
            acc[rt] = __builtin_amdgcn_mfma_f32_16x16x32_bf16(ah[rt], bl, acc[rt], 0, 0, 0);
            acc[rt] = __builtin_amdgcn_mfma_f32_16x16x32_bf16(al[rt], bh, acc[rt], 0, 0, 0);
        }
    }

    // ---- epilogue: C/D layout col=lane&15, row=(lane>>4)*4+reg
    const int oo = o0 + w * 16 + l15;
    const float b2v = b2[oo];
#pragma unroll
    for (int rt = 0; rt < 2; ++rt)
#pragma unroll
        for (int r = 0; r < 4; ++r) {
            const int pp = p0 + rt * 16 + l4 * 4 + r;
            h2[pp * FEAT + oo] = leaky(acc[rt][r] + b2v);
        }
}

// ---------------------------------------------------------------------------
// K4: per wi (32 blocks x 640 thr): c1 = mean_jj h2; m = c1^4;
//     V = -2*m*S (bf16 hi/lo), M = m (bf16 hi/lo)  [row-major [wi][f]];
//     alpha[wi] = sum_f m*S^2 (deterministic shuffle+LDS reduce).
__global__ __launch_bounds__(640) void k4_ctx(const float* __restrict__ h2,
                                              const float* __restrict__ S,
                                              unsigned short* __restrict__ Vhi,
                                              unsigned short* __restrict__ Vlo,
                                              unsigned short* __restrict__ Mhi,
                                              unsigned short* __restrict__ Mlo,
                                              float* __restrict__ alpha) {
    __shared__ float red[10];
    const int wi = blockIdx.x;
    const int o  = threadIdx.x;
    float s = 0.0f;
#pragma unroll 31
    for (int jj = 0; jj < 31; ++jj)
        s += h2[(wi * 31 + jj) * FEAT + o];
    float c1 = s * (1.0f / 31.0f);
    float c2 = c1 * c1;
    float m  = c2 * c2;
    float sv = S[wi * FEAT + o];
    float vm = -2.0f * m * sv;
    short h, l;
    split2(vm, h, l);
    Vhi[wi * FEAT + o] = (unsigned short)h;
    Vlo[wi * FEAT + o] = (unsigned short)l;
    split2(m, h, l);
    Mhi[wi * FEAT + o] = (unsigned short)h;
    Mlo[wi * FEAT + o] = (unsigned short)l;

    float part = m * sv * sv;
#pragma unroll
    for (int off = 32; off > 0; off >>= 1)
        part += __shfl_down(part, off, 64);
    if ((o & 63) == 0) red[o >> 6] = part;
    __syncthreads();
    if (o == 0) {
        float t = 0.0f;
#pragma unroll
        for (int k = 0; k < 10; ++k) t += red[k];
        alpha[wi] = t;
    }
}

// ---------------------------------------------------------------------------
// K5: out[q,wi] = -sqrt( alpha[wi] + sum_f V[wi,f]*Q[q,f] + sum_f M[wi,f]*Q[q,f]^2 )
// MFMA skinny GEMM: 256 blocks x 4 waves; block = 16 q x 32 wi; waves K-split
// (160 f each). B-frags (V/M hi/lo) read directly from global (L2-resident);
// Q split to bf16 on the fly. Deterministic LDS combine of the 4 partials.
__global__ __launch_bounds__(256) void k5_mfma(const float* __restrict__ Q,
                                               const unsigned short* __restrict__ Vhi,
                                               const unsigned short* __restrict__ Vlo,
                                               const unsigned short* __restrict__ Mhi,
                                               const unsigned short* __restrict__ Mlo,
                                               const float* __restrict__ alpha,
                                               float* __restrict__ out) {
    __shared__ float red[4][16][32];
    const int q0 = blockIdx.x * 16;
    const int tid = threadIdx.x;
    const int w    = tid >> 6;
    const int lane = tid & 63;
    const int l15 = lane & 15, l4 = lane >> 4;
    const float* Qrow = Q + (size_t)(q0 + l15) * FEAT + l4 * 8;

    f32x4 acc[2] = {};

    for (int s = 0; s < 5; ++s) {
        const int k0 = w * 160 + s * 32;
        float4 qa = *(const float4*)(Qrow + k0);
        float4 qb = *(const float4*)(Qrow + k0 + 4);
        float qs[8] = {qa.x, qa.y, qa.z, qa.w, qb.x, qb.y, qb.z, qb.w};
        bf16x8 qh, ql, q2h;
#pragma unroll
        for (int j = 0; j < 8; ++j) {
            short h, l;
            split2(qs[j], h, l);
            qh[j] = h; ql[j] = l;
            q2h[j] = (short)bf16_rne(qs[j] * qs[j]);
        }
#pragma unroll
        for (int ct = 0; ct < 2; ++ct) {
            const int wi = ct * 16 + l15;
            const size_t bo = (size_t)wi * FEAT + k0 + l4 * 8;
            bf16x8 fvh = *(const bf16x8*)(Vhi + bo);
            bf16x8 fvl = *(const bf16x8*)(Vlo + bo);
            bf16x8 fmh = *(const bf16x8*)(Mhi + bo);
            bf16x8 fml = *(const bf16x8*)(Mlo + bo);
            acc[ct] = __builtin_amdgcn_mfma_f32_16x16x32_bf16(qh,  fvh, acc[ct], 0, 0, 0);
            acc[ct] = __builtin_amdgcn_mfma_f32_16x16x32_bf16(ql,  fvh, acc[ct], 0, 0, 0);
            acc[ct] = __builtin_amdgcn_mfma_f32_16x16x32_bf16(qh,  fvl, acc[ct], 0, 0, 0);
            acc[ct] = __builtin_amdgcn_mfma_f32_16x16x32_bf16(q2h, fmh, acc[ct], 0, 0, 0);
            acc[ct] = __builtin_amdgcn_mfma_f32_16x16x32_bf16(q2h, fml, acc[ct], 0, 0, 0);
        }
    }

#pragma unroll
    for (int ct = 0; ct < 2; ++ct)
#pragma unroll
        for (int r = 0; r < 4; ++r)
            red[w][l4 * 4 + r][ct * 16 + l15] = acc[ct][r];
    __syncthreads();

#pragma unroll
    for (int e = tid; e < 512; e += 256) {
        const int qs_ = e >> 5, wi = e & 31;
        float v = red[0][qs_][wi] + red[1][qs_][wi] + red[2][qs_][wi] + red[3][qs_][wi];
        float d2 = alpha[wi] + v;
        out[(q0 + qs_) * WAY + wi] = -sqrtf(fmaxf(d2, 0.0f));
    }
}

extern "C" void kernel_launch(void* const* d_in, const int* in_sizes, int n_in,
                              void* d_out, int out_size, void* d_ws, size_t ws_size,
                              hipStream_t stream) {
    const float* S  = (const float*)d_in[0];   // [32, 640]
    const float* Q  = (const float*)d_in[1];   // [4096, 640]
    const float* W1 = (const float*)d_in[2];   // [640, 1280]
    const float* b1 = (const float*)d_in[3];   // [640]
    const float* W2 = (const float*)d_in[4];   // [640, 640]
    const float* b2 = (const float*)d_in[5];   // [640]
    float* out = (float*)d_out;                // [4096, 32]

    char* wsb = (char*)d_ws;
    float* A    = (float*)wsb;                                  // 32*640 f32
    float* B    = A + WAY * FEAT;                               // 32*640 f32
    float* h2   = B + WAY * FEAT;                               // 992*640 f32
    float* alpha = h2 + NPAIR * FEAT;                           // 32 f32 (+pad)
    unsigned short* whi = (unsigned short*)(alpha + 64);        // 640*640 u16
    unsigned short* wlo = whi + FEAT * FEAT;                    // 640*640 u16
    unsigned short* Vhi = wlo + FEAT * FEAT;                    // 32*640 u16
    unsigned short* Vlo = Vhi + WAY * FEAT;
    unsigned short* Mhi = Vlo + WAY * FEAT;
    unsigned short* Mlo = Mhi + WAY * FEAT;
    (void)ws_size; (void)in_sizes; (void)n_in; (void)out_size;

    k_pre<<<dim3(720), dim3(256), 0, stream>>>(S, W1, b1, W2, A, B, whi, wlo);
    k3_mfma<<<dim3(31, 10), dim3(256), 0, stream>>>(A, B, whi, wlo, b2, h2);
    k4_ctx<<<dim3(WAY), dim3(640), 0, stream>>>(h2, S, Vhi, Vlo, Mhi, Mlo, alpha);
    k5_mfma<<<dim3(WQ / 16), dim3(256), 0, stream>>>(Q, Vhi, Vlo, Mhi, Mlo, alpha, out);
}